// Round 1
// baseline (4753.659 us; speedup 1.0000x reference)
//
#include <hip/hip_runtime.h>

#define B_ 16
#define C_ 256
#define N_ 4096
#define NH_ 8
#define D_ 64
#define HD_ 512
#define NCH_ 8
#define CHN_ 512

typedef unsigned short u16;
typedef unsigned int u32;

__device__ __forceinline__ float bf2f(u16 b){ union{u32 u; float f;} v; v.u=((u32)b)<<16; return v.f; }
__device__ __forceinline__ u16 f2bf(float f){ union{float f; u32 u;} v; v.f=f; return (u16)((v.u + 0x7FFFu + ((v.u>>16)&1u))>>16); }

// ---------------- kernel 1: per-pixel 16/max(||x||,eps) ----------------
__global__ __launch_bounds__(256) void k_rnorm(const float* __restrict__ x, float* __restrict__ rn){
  int p = blockIdx.x*256 + threadIdx.x;
  int b = p>>12, n = p&4095;
  const float* xp = x + (size_t)b*C_*N_ + n;
  float s = 0.f;
  #pragma unroll 8
  for (int c=0;c<C_;c++){ float v = xp[(size_t)c*N_]; s = fmaf(v,v,s); }
  rn[p] = 16.0f / fmaxf(sqrtf(s), 1e-12f);
}

// ---------------- kernel 2: k-row online softmax stats per n-chunk ----------------
__global__ __launch_bounds__(256) void k_kstats(const float* __restrict__ x, const float* __restrict__ qkvw,
    const float* __restrict__ nw, const float* __restrict__ rn,
    float* __restrict__ stat_m, float* __restrict__ stat_s){
  __shared__ float wk[64*129];
  __shared__ float xs[128*32];
  __shared__ float red[64*9];
  const int ch = blockIdx.x, h = blockIdx.y, b = blockIdx.z;
  const int tid = threadIdx.x;
  const int dd = tid & 31, jg = tid >> 5;
  const int j0 = jg*4;
  const int r0 = 2*dd, r1 = r0+1;
  float m0=-1e30f, m1=-1e30f, s0=0.f, s1=0.f;
  for (int t=0;t<16;++t){
    const int n0 = ch*CHN_ + t*32;
    float ka[2][4] = {{0.f,0.f,0.f,0.f},{0.f,0.f,0.f,0.f}};
    for (int half=0; half<2; ++half){
      __syncthreads();
      #pragma unroll
      for (int i=0;i<32;i++){
        int f = i*256 + tid; int row = f>>7, cc2 = f&127;
        wk[row*129+cc2] = qkvw[(size_t)(HD_ + h*64 + row)*C_ + half*128 + cc2];
      }
      #pragma unroll
      for (int i=0;i<16;i++){
        int f = i*256 + tid; int cc2 = f>>5, l = f&31;
        int cg = half*128 + cc2;
        xs[cc2*32+l] = x[(size_t)b*C_*N_ + (size_t)cg*N_ + n0 + l] * rn[b*N_+n0+l] * nw[cg];
      }
      __syncthreads();
      #pragma unroll 8
      for (int cc2=0; cc2<128; ++cc2){
        float w0 = wk[r0*129+cc2], w1 = wk[r1*129+cc2];
        const float4 xv = *(const float4*)&xs[cc2*32 + j0];
        ka[0][0]=fmaf(w0,xv.x,ka[0][0]); ka[0][1]=fmaf(w0,xv.y,ka[0][1]);
        ka[0][2]=fmaf(w0,xv.z,ka[0][2]); ka[0][3]=fmaf(w0,xv.w,ka[0][3]);
        ka[1][0]=fmaf(w1,xv.x,ka[1][0]); ka[1][1]=fmaf(w1,xv.y,ka[1][1]);
        ka[1][2]=fmaf(w1,xv.z,ka[1][2]); ka[1][3]=fmaf(w1,xv.w,ka[1][3]);
      }
    }
    float pm0 = fmaxf(fmaxf(ka[0][0],ka[0][1]),fmaxf(ka[0][2],ka[0][3]));
    float pm1 = fmaxf(fmaxf(ka[1][0],ka[1][1]),fmaxf(ka[1][2],ka[1][3]));
    red[r0*9+jg]=pm0; red[r1*9+jg]=pm1;
    __syncthreads();
    float mt0=m0, mt1=m1;
    #pragma unroll
    for (int g=0;g<8;g++){ mt0=fmaxf(mt0,red[r0*9+g]); mt1=fmaxf(mt1,red[r1*9+g]); }
    float ps0 = __expf(ka[0][0]-mt0)+__expf(ka[0][1]-mt0)+__expf(ka[0][2]-mt0)+__expf(ka[0][3]-mt0);
    float ps1 = __expf(ka[1][0]-mt1)+__expf(ka[1][1]-mt1)+__expf(ka[1][2]-mt1)+__expf(ka[1][3]-mt1);
    __syncthreads();
    red[r0*9+jg]=ps0; red[r1*9+jg]=ps1;
    __syncthreads();
    float st0=0.f, st1=0.f;
    #pragma unroll
    for (int g=0;g<8;g++){ st0+=red[r0*9+g]; st1+=red[r1*9+g]; }
    s0 = s0*__expf(m0-mt0) + st0; m0 = mt0;
    s1 = s1*__expf(m1-mt1) + st1; m1 = mt1;
  }
  if (jg==0){
    int rg = (b*NH_ + h)*D_ + r0;
    stat_m[rg*NCH_+ch]=m0; stat_s[rg*NCH_+ch]=s0;
    stat_m[(rg+1)*NCH_+ch]=m1; stat_s[(rg+1)*NCH_+ch]=s1;
  }
}

// ---------------- kernel 3: combine chunk stats ----------------
__global__ __launch_bounds__(256) void k_statcomb(const float* __restrict__ stat_m, const float* __restrict__ stat_s,
    float* __restrict__ Mrow, float* __restrict__ Sinv){
  int r = blockIdx.x*256 + threadIdx.x; // 8192 rows
  float M = -1e30f;
  #pragma unroll
  for (int ch=0; ch<NCH_; ch++) M = fmaxf(M, stat_m[r*NCH_+ch]);
  float S = 0.f;
  #pragma unroll
  for (int ch=0; ch<NCH_; ch++) S += stat_s[r*NCH_+ch]*__expf(stat_m[r*NCH_+ch]-M);
  Mrow[r]=M; Sinv[r]=1.0f/S;
}

// ---------------- kernel 4: ctx partials per n-chunk ----------------
__global__ __launch_bounds__(256) void k_ctx(const float* __restrict__ x, const float* __restrict__ qkvw,
    const float* __restrict__ nw, const float* __restrict__ rn,
    const float* __restrict__ Mrow, const float* __restrict__ Sinv, float* __restrict__ ctxp){
  __shared__ float wkv[2*64*65];   // k,v weight tiles (64 c at a time)
  __shared__ float xs[64*32];
  __shared__ float pb[64*36];      // softmaxed k tile
  __shared__ float vs[64*36];      // v tile
  const int ch=blockIdx.x, h=blockIdx.y, b=blockIdx.z, tid=threadIdx.x;
  const int d = tid&63, jg = tid>>6, j0 = jg*8;
  const int dg = tid&15, eg = tid>>4;
  const int rg = (b*NH_+h)*D_ + d;
  const float Md = Mrow[rg], iS = Sinv[rg];
  float acc[4][4] = {{0.f,0.f,0.f,0.f},{0.f,0.f,0.f,0.f},{0.f,0.f,0.f,0.f},{0.f,0.f,0.f,0.f}};
  for (int t=0;t<16;++t){
    const int n0 = ch*CHN_ + t*32;
    float ka[8]={0.f,0.f,0.f,0.f,0.f,0.f,0.f,0.f};
    float va[8]={0.f,0.f,0.f,0.f,0.f,0.f,0.f,0.f};
    for (int q4=0;q4<4;++q4){
      __syncthreads();
      #pragma unroll
      for (int i=0;i<32;i++){
        int f=i*256+tid; int m=f>>12, rem=f&4095; int row=rem>>6, cc2=rem&63;
        wkv[(m*64+row)*65+cc2] = qkvw[(size_t)(HD_ + m*HD_ + h*64+row)*C_ + q4*64+cc2];
      }
      #pragma unroll
      for (int i=0;i<8;i++){
        int f=i*256+tid; int cc2=f>>5, l=f&31; int cg=q4*64+cc2;
        xs[cc2*32+l] = x[(size_t)b*C_*N_ + (size_t)cg*N_ + n0+l] * rn[b*N_+n0+l] * nw[cg];
      }
      __syncthreads();
      #pragma unroll 8
      for (int cc2=0;cc2<64;++cc2){
        float w0 = wkv[d*65+cc2];
        float w1 = wkv[(64+d)*65+cc2];
        const float4 xa = *(const float4*)&xs[cc2*32+j0];
        const float4 xb = *(const float4*)&xs[cc2*32+j0+4];
        ka[0]=fmaf(w0,xa.x,ka[0]); ka[1]=fmaf(w0,xa.y,ka[1]); ka[2]=fmaf(w0,xa.z,ka[2]); ka[3]=fmaf(w0,xa.w,ka[3]);
        ka[4]=fmaf(w0,xb.x,ka[4]); ka[5]=fmaf(w0,xb.y,ka[5]); ka[6]=fmaf(w0,xb.z,ka[6]); ka[7]=fmaf(w0,xb.w,ka[7]);
        va[0]=fmaf(w1,xa.x,va[0]); va[1]=fmaf(w1,xa.y,va[1]); va[2]=fmaf(w1,xa.z,va[2]); va[3]=fmaf(w1,xa.w,va[3]);
        va[4]=fmaf(w1,xb.x,va[4]); va[5]=fmaf(w1,xb.y,va[5]); va[6]=fmaf(w1,xb.z,va[6]); va[7]=fmaf(w1,xb.w,va[7]);
      }
    }
    #pragma unroll
    for (int jj=0;jj<8;jj++){
      pb[d*36 + j0+jj] = __expf(ka[jj]-Md)*iS;
      vs[d*36 + j0+jj] = va[jj];
    }
    __syncthreads();
    #pragma unroll
    for (int j=0;j<32;j+=4){
      float pv[4][4], vv[4][4];
      #pragma unroll
      for (int dr=0;dr<4;dr++){
        const float4 pf = *(const float4*)&pb[(dg*4+dr)*36 + j];
        pv[dr][0]=pf.x; pv[dr][1]=pf.y; pv[dr][2]=pf.z; pv[dr][3]=pf.w;
      }
      #pragma unroll
      for (int er=0;er<4;er++){
        const float4 vf = *(const float4*)&vs[(eg*4+er)*36 + j];
        vv[er][0]=vf.x; vv[er][1]=vf.y; vv[er][2]=vf.z; vv[er][3]=vf.w;
      }
      #pragma unroll
      for (int dr=0;dr<4;dr++)
        #pragma unroll
        for (int er=0;er<4;er++)
          #pragma unroll
          for (int qq=0;qq<4;qq++)
            acc[dr][er] = fmaf(pv[dr][qq], vv[er][qq], acc[dr][er]);
    }
  }
  __syncthreads();
  float* ctxs = wkv; // reuse
  #pragma unroll
  for (int dr=0;dr<4;dr++)
    #pragma unroll
    for (int er=0;er<4;er++)
      ctxs[(dg*4+dr)*66 + eg*4+er] = acc[dr][er];
  __syncthreads();
  size_t base = ((size_t)(ch*B_ + b)*NH_ + h)*4096;
  #pragma unroll
  for (int i=0;i<16;i++){ int f=i*256+tid; ctxp[base+f] = ctxs[(f>>6)*66 + (f&63)]; }
}

// ---------------- kernel 5: reduce ctx partials ----------------
__global__ __launch_bounds__(256) void k_ctxred(const float* __restrict__ ctxp, float* __restrict__ ctx){
  int i = blockIdx.x*256 + threadIdx.x; // 524288
  float s=0.f;
  #pragma unroll
  for (int ch=0; ch<NCH_; ch++) s += ctxp[(size_t)ch*524288 + i];
  ctx[i]=s;
}

// ---------------- kernel 6: fused q-GEMM + q-softmax + attention + out-GEMM + RMSnorm ----------------
__global__ __launch_bounds__(256) void k_final(const float* __restrict__ x, const float* __restrict__ qkvw,
    const float* __restrict__ nw, const float* __restrict__ rn, const float* __restrict__ ctx,
    const float* __restrict__ ow, const float* __restrict__ ob, const float* __restrict__ onw,
    float* __restrict__ out){
  __shared__ float bufA[6176];   // xs[256*16]+wq[32*65] / qb(bf16 512*20) / owt[256*17] / res[256*17]+rr[16]
  __shared__ float bufB[8704];   // q[512*17] / att[16*524]
  const int tid = threadIdx.x;
  const int p0 = blockIdx.x*16;
  const int b = p0>>12, n0 = p0&4095;
  // phase 1: stage normalized x tile
  float* xs = bufA;
  float* wq = bufA + 4096;
  #pragma unroll
  for (int i=0;i<16;i++){
    int f=i*256+tid; int c=f>>4, l=f&15;
    xs[c*16+l] = x[(size_t)b*C_*N_ + (size_t)c*N_ + n0+l] * rn[p0+l] * nw[c];
  }
  // phase 2: q = Wq * xn
  float* q = bufB;
  const int r = tid&31, jh = tid>>5; const int j0q = jh*2;
  for (int g=0; g<16; ++g){
    float qa0=0.f, qa1=0.f;
    for (int chk=0; chk<4; ++chk){
      __syncthreads();
      #pragma unroll
      for (int i=0;i<8;i++){
        int f=i*256+tid; int row=f>>6, cc2=f&63;
        wq[row*65+cc2] = qkvw[(size_t)(g*32+row)*C_ + chk*64 + cc2];
      }
      __syncthreads();
      #pragma unroll 8
      for (int cc2=0;cc2<64;++cc2){
        float w = wq[r*65+cc2];
        const float2 xv = *(const float2*)&xs[(chk*64+cc2)*16 + j0q];
        qa0 = fmaf(w, xv.x, qa0); qa1 = fmaf(w, xv.y, qa1);
      }
    }
    q[(g*32+r)*17 + j0q] = qa0; q[(g*32+r)*17 + j0q+1] = qa1;
  }
  __syncthreads();
  // phase 3: softmax over d per (head, pixel), * 1/8, to bf16
  u16* qb = (u16*)bufA; // [512][20]
  if (tid < 128){
    const int j = tid&15, hh = tid>>4;
    float mx = -1e30f;
    for (int dq=0;dq<64;dq++) mx = fmaxf(mx, q[(hh*64+dq)*17 + j]);
    float sm = 0.f;
    for (int dq=0;dq<64;dq++) sm += __expf(q[(hh*64+dq)*17 + j] - mx);
    float inv = 0.125f/sm;
    for (int dq=0;dq<64;dq++) qb[(hh*64+dq)*20 + j] = f2bf(__expf(q[(hh*64+dq)*17+j]-mx)*inv);
  }
  __syncthreads();
  // phase 4: att[e_glob][j] = sum_d ctx[b,h,d,e] * q_sm[h*64+d][j]   (att stored j-major)
  float* att = bufB; // [16][524]
  {
    const int e = tid&63, jg2 = tid>>6; const int j0a = jg2*4;
    for (int hh=0; hh<8; ++hh){
      float a0=0.f,a1=0.f,a2=0.f,a3=0.f;
      const float* cb = ctx + ((size_t)(b*NH_+hh))*4096 + e;
      #pragma unroll 4
      for (int dq=0;dq<64;dq++){
        float cv = cb[dq*64];
        const ushort4 qu = *(const ushort4*)&qb[(hh*64+dq)*20 + j0a];
        a0 = fmaf(cv, bf2f(qu.x), a0); a1 = fmaf(cv, bf2f(qu.y), a1);
        a2 = fmaf(cv, bf2f(qu.z), a2); a3 = fmaf(cv, bf2f(qu.w), a3);
      }
      att[(j0a+0)*524 + hh*64+e] = a0;
      att[(j0a+1)*524 + hh*64+e] = a1;
      att[(j0a+2)*524 + hh*64+e] = a2;
      att[(j0a+3)*524 + hh*64+e] = a3;
    }
  }
  // phase 5: out GEMM [256,512] x att + bias
  float* owt = bufA; // [256][17]
  float oa[16];
  #pragma unroll
  for (int j=0;j<16;j++) oa[j] = ob[tid];
  float w16[16];
  for (int ecb=0; ecb<32; ++ecb){
    const int e0 = ecb*16;
    __syncthreads();
    #pragma unroll
    for (int i=0;i<16;i++){
      int f=i*256+tid; int row=f>>4, ee=f&15;
      owt[row*17+ee] = ow[(size_t)row*HD_ + e0+ee];
    }
    __syncthreads();
    #pragma unroll
    for (int ee=0;ee<16;ee++) w16[ee] = owt[tid*17+ee];
    #pragma unroll
    for (int j=0;j<16;j++){
      #pragma unroll
      for (int eq=0;eq<4;eq++){
        const float4 av = *(const float4*)&att[j*524 + e0 + eq*4];
        oa[j] = fmaf(w16[eq*4+0],av.x, oa[j]);
        oa[j] = fmaf(w16[eq*4+1],av.y, oa[j]);
        oa[j] = fmaf(w16[eq*4+2],av.z, oa[j]);
        oa[j] = fmaf(w16[eq*4+3],av.w, oa[j]);
      }
    }
  }
  // phase 6-8: final RMS norm over channels + store
  __syncthreads();
  float* res = bufA;        // [256][17]
  float* rr = bufA + 4352;  // [16]
  #pragma unroll
  for (int j=0;j<16;j++) res[tid*17+j] = oa[j];
  __syncthreads();
  if (tid<16){
    float ss=0.f;
    for (int o=0;o<256;o++){ float v=res[o*17+tid]; ss=fmaf(v,v,ss); }
    rr[tid] = 16.0f / fmaxf(sqrtf(ss), 1e-12f);
  }
  __syncthreads();
  const int jj2 = tid&15, og = tid>>4;
  #pragma unroll
  for (int i=0;i<16;i++){
    int o = og*16 + i;
    out[(size_t)b*C_*N_ + (size_t)o*N_ + n0 + jj2] = res[o*17+jj2] * rr[jj2] * onw[o];
  }
}

extern "C" void kernel_launch(void* const* d_in, const int* in_sizes, int n_in,
                              void* d_out, int out_size, void* d_ws, size_t ws_size,
                              hipStream_t stream){
  const float* x    = (const float*)d_in[0];
  const float* nw   = (const float*)d_in[1];
  const float* qkvw = (const float*)d_in[2];
  const float* ow   = (const float*)d_in[3];
  const float* ob   = (const float*)d_in[4];
  const float* onw  = (const float*)d_in[5];
  float* out = (float*)d_out;
  float* w = (float*)d_ws;
  float* rn     = w;              // 65536
  float* stat_m = w + 65536;      // 65536
  float* stat_s = w + 131072;     // 65536
  float* Mrow   = w + 196608;     // 8192
  float* Sinv   = w + 204800;     // 8192
  float* ctx    = w + 212992;     // 524288
  float* ctxp   = w + 737280;     // 8*524288 = 4194304
  (void)in_sizes; (void)n_in; (void)out_size; (void)ws_size;

  k_rnorm<<<256,256,0,stream>>>(x, rn);
  k_kstats<<<dim3(NCH_,NH_,B_),256,0,stream>>>(x,qkvw,nw,rn,stat_m,stat_s);
  k_statcomb<<<32,256,0,stream>>>(stat_m,stat_s,Mrow,Sinv);
  k_ctx<<<dim3(NCH_,NH_,B_),256,0,stream>>>(x,qkvw,nw,rn,Mrow,Sinv,ctxp);
  k_ctxred<<<2048,256,0,stream>>>(ctxp,ctx);
  k_final<<<4096,256,0,stream>>>(x,qkvw,nw,rn,ctx,ow,ob,onw,out);
}

// Round 2
// 495.197 us; speedup vs baseline: 9.5995x; 9.5995x over previous
//
#include <hip/hip_runtime.h>

#define C_ 256
#define N_ 4096
#define NH_ 8

typedef unsigned short u16;
typedef unsigned int u32;
typedef __attribute__((ext_vector_type(8))) short s8v;
typedef __attribute__((ext_vector_type(4))) float f4v;

#define MFMA16 __builtin_amdgcn_mfma_f32_16x16x32_bf16

__device__ __forceinline__ u16 f2bf(float f){ union{float f; u32 u;} v; v.f=f; return (u16)((v.u + 0x7FFFu + ((v.u>>16)&1u))>>16); }

// ---------------- kernel A1: pixel rnorm + write xnT[b][n][c] bf16 ----------------
__global__ __launch_bounds__(256) void k_prep(const float* __restrict__ x, const float* __restrict__ nw,
                                              u16* __restrict__ xnT){
  __shared__ float nws[256];
  const int tid = threadIdx.x;
  nws[tid] = nw[tid];
  __syncthreads();
  const int p = blockIdx.x*256 + tid;
  const int b = p>>12, n = p&4095;
  const float* xp = x + (size_t)b*(C_*N_) + n;
  float s = 0.f;
  #pragma unroll 8
  for (int c=0;c<C_;c++){ float v = xp[(size_t)c*N_]; s = fmaf(v,v,s); }
  const float r = 16.0f / fmaxf(sqrtf(s), 1e-12f);
  u16* o = xnT + (size_t)p*256;
  #pragma unroll 4
  for (int c=0;c<C_;c+=2){
    float v0 = xp[(size_t)c*N_]     * r * nws[c];
    float v1 = xp[(size_t)(c+1)*N_] * r * nws[c+1];
    *(u32*)(o + c) = (u32)f2bf(v0) | ((u32)f2bf(v1)<<16);
  }
}

// ---------------- kernel A2: weights -> bf16 ----------------
__global__ __launch_bounds__(256) void k_wconv(const float* __restrict__ qkvw, const float* __restrict__ ow,
                                               u16* __restrict__ wqkv, u16* __restrict__ owb){
  int i = blockIdx.x*256 + threadIdx.x;   // 524288 total
  if (i < 393216) wqkv[i] = f2bf(qkvw[i]);
  else            owb[i-393216] = f2bf(ow[i-393216]);
}

// ---------------- kernel B: K/V GEMM + flash softmax over n + ctx partials ----------------
// grid (ch=4, h=8, b=16), 256 threads (4 waves). Each chunk covers 1024 pixels, 8 tiles of 128.
__global__ __launch_bounds__(256,2) void k_kv(const u16* __restrict__ xnT, const u16* __restrict__ wqkv,
    float* __restrict__ ctxp, float* __restrict__ Mp, float* __restrict__ Sp){
  __shared__ float kbuf[64*133];      // f32 k tile, stride 133; aliased later as pbuf bf16 stride 136
  __shared__ u16   vbuf[64*136];
  __shared__ float redm[64*4];
  __shared__ float reds[64*4];
  __shared__ float fbuf[64];
  const int ch=blockIdx.x, h=blockIdx.y, b=blockIdx.z;
  const int tid=threadIdx.x, w=tid>>6, l=tid&63, l15=l&15, lg=l>>4;
  const int sr = tid&63, sg = tid>>6;   // softmax row/segment
  u16* pbuf = (u16*)kbuf;

  // resident W A-frags: k rows 512+h*64+w*16+l15, v rows +512
  s8v ak[8], av[8];
  {
    const u16* wkp = wqkv + (size_t)(512 + h*64 + w*16 + l15)*256 + lg*8;
    const u16* wvp = wkp + 512*256;
    #pragma unroll
    for (int cs=0; cs<8; cs++){ ak[cs] = *(const s8v*)(wkp + cs*32); av[cs] = *(const s8v*)(wvp + cs*32); }
  }
  f4v acc[4];
  #pragma unroll
  for (int et=0;et<4;et++) acc[et] = (f4v){0.f,0.f,0.f,0.f};
  float M = -1e30f, S = 0.f;
  const u16* xb = xnT + (size_t)b*(4096*256);

  for (int t=0; t<8; ++t){
    const int n0 = ch*1024 + t*128;
    // GEMM1: k,v [16 rows][128 n] per wave
    f4v kacc[8], vacc[8];
    #pragma unroll
    for (int ns=0;ns<8;ns++){ kacc[ns]=(f4v){0.f,0.f,0.f,0.f}; vacc[ns]=(f4v){0.f,0.f,0.f,0.f}; }
    #pragma unroll
    for (int ns=0; ns<8; ns++){
      const u16* rp = xb + (size_t)(n0 + ns*16 + l15)*256 + lg*8;
      #pragma unroll
      for (int cs=0; cs<8; cs++){
        s8v bfr = *(const s8v*)(rp + cs*32);
        kacc[ns] = MFMA16(ak[cs], bfr, kacc[ns], 0,0,0);
        vacc[ns] = MFMA16(av[cs], bfr, vacc[ns], 0,0,0);
      }
    }
    __syncthreads();   // prev-tile pbuf/vbuf readers done
    #pragma unroll
    for (int ns=0; ns<8; ns++)
      #pragma unroll
      for (int j=0;j<4;j++){
        int row = w*16 + lg*4 + j, col = ns*16 + l15;
        kbuf[row*133+col] = kacc[ns][j];
        vbuf[row*136+col] = f2bf(vacc[ns][j]);
      }
    __syncthreads();
    // softmax over this tile's 128 cols: thread (sr,sg) owns cols sg*32..+31 of row sr
    float kv[32];
    #pragma unroll
    for (int i=0;i<32;i++) kv[i] = kbuf[sr*133 + sg*32 + i];
    float mx = kv[0];
    #pragma unroll
    for (int i=1;i<32;i++) mx = fmaxf(mx, kv[i]);
    redm[sr*4+sg] = mx;
    __syncthreads();   // also: all kv reads complete before pbuf overwrite
    float Mt = fmaxf(fmaxf(redm[sr*4],redm[sr*4+1]),fmaxf(redm[sr*4+2],redm[sr*4+3]));
    float Mn = fmaxf(M, Mt);
    float f  = __expf(M - Mn);
    float ps = 0.f;
    #pragma unroll
    for (int i=0;i<32;i++){
      float e = __expf(kv[i]-Mn);
      ps += e;
      pbuf[sr*136 + sg*32 + i] = f2bf(e);
    }
    reds[sr*4+sg] = ps;
    if (sg==0) fbuf[sr] = f;
    M = Mn;
    __syncthreads();
    S = S*f + (reds[sr*4]+reds[sr*4+1]+reds[sr*4+2]+reds[sr*4+3]);
    // rescale ctx acc rows by fbuf
    #pragma unroll
    for (int j=0;j<4;j++){
      float fj = fbuf[w*16 + lg*4 + j];
      #pragma unroll
      for (int et=0;et<4;et++) acc[et][j] *= fj;
    }
    // GEMM2: ctx[d][e] += p[d][n-tile] * v^T
    #pragma unroll
    for (int ks=0; ks<4; ks++){
      s8v af = *(const s8v*)(pbuf + (w*16+l15)*136 + ks*32 + lg*8);
      #pragma unroll
      for (int et=0; et<4; et++){
        s8v bv = *(const s8v*)(vbuf + (et*16+l15)*136 + ks*32 + lg*8);
        acc[et] = MFMA16(af, bv, acc[et], 0,0,0);
      }
    }
  }
  // outputs: ctxp[ch][b][h][d][e], Mp/Sp[ch][b][h][d]
  float* cp = ctxp + (((size_t)ch*16 + b)*8 + h)*4096;
  #pragma unroll
  for (int et=0; et<4; et++)
    #pragma unroll
    for (int j=0;j<4;j++)
      cp[(w*16+lg*4+j)*64 + et*16+l15] = acc[et][j];
  if (sg==0){
    int rg = (b*8+h)*64 + sr;
    Mp[ch*8192+rg]=M; Sp[ch*8192+rg]=S;
  }
}

// ---------------- kernel C: combine chunk partials -> ctxT[b][h][e][d] bf16 ----------------
__global__ __launch_bounds__(256) void k_comb(const float* __restrict__ ctxp, const float* __restrict__ Mp,
    const float* __restrict__ Sp, u16* __restrict__ ctxT){
  __shared__ float fs[4][64];
  __shared__ float iS[64];
  const int bh = blockIdx.x, tid = threadIdx.x;
  if (tid < 64){
    int rg = bh*64 + tid;
    float m0=Mp[rg], m1=Mp[8192+rg], m2=Mp[16384+rg], m3=Mp[24576+rg];
    float Mg = fmaxf(fmaxf(m0,m1),fmaxf(m2,m3));
    float f0=__expf(m0-Mg), f1=__expf(m1-Mg), f2=__expf(m2-Mg), f3=__expf(m3-Mg);
    float Sg = Sp[rg]*f0 + Sp[8192+rg]*f1 + Sp[16384+rg]*f2 + Sp[24576+rg]*f3;
    fs[0][tid]=f0; fs[1][tid]=f1; fs[2][tid]=f2; fs[3][tid]=f3;
    iS[tid] = 1.0f / Sg;
  }
  __syncthreads();
  const int e = tid>>2, d0 = (tid&3)*16;
  const float* cpb = ctxp + (size_t)bh*4096;
  u16* op = ctxT + (size_t)bh*4096 + e*64 + d0;
  #pragma unroll
  for (int i=0;i<16;i++){
    int d = d0+i;
    float v = cpb[d*64+e]*fs[0][d] + cpb[524288+d*64+e]*fs[1][d]
            + cpb[1048576+d*64+e]*fs[2][d] + cpb[1572864+d*64+e]*fs[3][d];
    op[i] = f2bf(v * iS[d]);
  }
}

// ---------------- kernel D: q-GEMM + q-softmax + att + out-GEMM + bias + RMS ----------------
// grid 1024 = (b, tile of 64 pixels); wave w owns 16 pixels. No cross-wave deps.
__global__ __launch_bounds__(256,2) void k_qout(const u16* __restrict__ xnT, const u16* __restrict__ wqkv,
    const u16* __restrict__ owb, const u16* __restrict__ ctxT,
    const float* __restrict__ ob, const float* __restrict__ onw, float* __restrict__ out){
  __shared__ u16 qstage[4][16*72];
  __shared__ u16 astage[4][16*72];
  __shared__ float obs[256], onws[256];
  const int tid = threadIdx.x;
  obs[tid]=ob[tid]; onws[tid]=onw[tid];
  __syncthreads();
  const int w=tid>>6, l=tid&63, l15=l&15, lg=l>>4;
  const int blk=blockIdx.x, b=blk>>6, n0=(blk&63)*64 + w*16;
  const u16* xb = xnT + ((size_t)b*4096 + n0)*256;
  u16* qs  = qstage[w];
  u16* as_ = astage[w];
  // resident xn A-frags (m = pixel row l15)
  s8v ax[8];
  #pragma unroll
  for (int cs=0;cs<8;cs++) ax[cs] = *(const s8v*)(xb + (size_t)l15*256 + cs*32 + lg*8);
  f4v oacc[16];
  #pragma unroll
  for (int mt=0;mt<16;mt++) oacc[mt] = (f4v){0.f,0.f,0.f,0.f};

  for (int h=0; h<8; ++h){
    // q-GEMM (transposed output): D[n-local][dout], dout tiles 4
    f4v qacc[4];
    #pragma unroll
    for (int dt=0;dt<4;dt++) qacc[dt] = (f4v){0.f,0.f,0.f,0.f};
    #pragma unroll
    for (int dt=0; dt<4; dt++){
      const u16* wq = wqkv + (size_t)(h*64 + dt*16 + l15)*256 + lg*8;
      #pragma unroll
      for (int cs=0; cs<8; cs++){
        s8v bw = *(const s8v*)(wq + cs*32);
        qacc[dt] = MFMA16(ax[cs], bw, qacc[dt], 0,0,0);
      }
    }
    // softmax over d (64) per pixel row; rows n = lg*4+j, cols d = dt*16+l15
    #pragma unroll
    for (int j=0;j<4;j++){
      float m = fmaxf(fmaxf(qacc[0][j],qacc[1][j]),fmaxf(qacc[2][j],qacc[3][j]));
      #pragma unroll
      for (int d=1; d<16; d<<=1) m = fmaxf(m, __shfl_xor(m, d));
      float s = 0.f;
      #pragma unroll
      for (int dt=0;dt<4;dt++){ float e=__expf(qacc[dt][j]-m); qacc[dt][j]=e; s+=e; }
      #pragma unroll
      for (int d=1; d<16; d<<=1) s += __shfl_xor(s, d);
      float inv = 0.125f/s;
      #pragma unroll
      for (int dt=0;dt<4;dt++) qs[(lg*4+j)*72 + dt*16+l15] = f2bf(qacc[dt][j]*inv);
    }
    // att-GEMM: D[n-local][e] = sum_d q_sm[n][d] * ctx[d][e]; B from ctxT[b][h][e][d]
    f4v aacc[4];
    #pragma unroll
    for (int et=0;et<4;et++) aacc[et] = (f4v){0.f,0.f,0.f,0.f};
    const u16* cxb = ctxT + ((size_t)(b*8+h))*4096;
    #pragma unroll
    for (int ks=0; ks<2; ks++){
      s8v aq = *(const s8v*)(qs + l15*72 + ks*32 + lg*8);
      #pragma unroll
      for (int et=0; et<4; et++){
        s8v bc = *(const s8v*)(cxb + (et*16+l15)*64 + ks*32 + lg*8);
        aacc[et] = MFMA16(aq, bc, aacc[et], 0,0,0);
      }
    }
    #pragma unroll
    for (int et=0;et<4;et++)
      #pragma unroll
      for (int j=0;j<4;j++)
        as_[(lg*4+j)*72 + et*16+l15] = f2bf(aacc[et][j]);
    // out-GEMM partial over this head's e-range: D[cout][n-local]
    #pragma unroll
    for (int ks=0; ks<2; ks++){
      s8v ba = *(const s8v*)(as_ + l15*72 + ks*32 + lg*8);
      #pragma unroll
      for (int mt=0; mt<16; mt++){
        s8v aw = *(const s8v*)(owb + (size_t)(mt*16+l15)*512 + h*64 + ks*32 + lg*8);
        oacc[mt] = MFMA16(aw, ba, oacc[mt], 0,0,0);
      }
    }
  }
  // bias + RMS over channels (per pixel col l15) + store
  float ss = 0.f;
  #pragma unroll
  for (int mt=0;mt<16;mt++)
    #pragma unroll
    for (int j=0;j<4;j++){
      float v = oacc[mt][j] + obs[mt*16+lg*4+j];
      oacc[mt][j] = v;
      ss = fmaf(v,v,ss);
    }
  ss += __shfl_xor(ss, 16);
  ss += __shfl_xor(ss, 32);
  const float r = 16.0f / fmaxf(sqrtf(ss), 1e-12f);
  float* op = out + (size_t)b*(256*4096) + n0 + l15;
  #pragma unroll
  for (int mt=0;mt<16;mt++)
    #pragma unroll
    for (int j=0;j<4;j++){
      int cout = mt*16+lg*4+j;
      op[(size_t)cout*4096] = oacc[mt][j] * r * onws[cout];
    }
}

extern "C" void kernel_launch(void* const* d_in, const int* in_sizes, int n_in,
                              void* d_out, int out_size, void* d_ws, size_t ws_size,
                              hipStream_t stream){
  const float* x    = (const float*)d_in[0];
  const float* nw   = (const float*)d_in[1];
  const float* qkvw = (const float*)d_in[2];
  const float* ow   = (const float*)d_in[3];
  const float* ob   = (const float*)d_in[4];
  const float* onw  = (const float*)d_in[5];
  float* out = (float*)d_out;
  char* ws = (char*)d_ws;
  u16*   xnT  = (u16*)(ws);                    // 33,554,432 B
  u16*   wqkv = (u16*)(ws + 33554432);         //    786,432 B
  u16*   owb  = (u16*)(ws + 34340864);         //    262,144 B
  u16*   ctxT = (u16*)(ws + 34603008);         //  1,048,576 B
  float* ctxp = (float*)(ws + 35651584);       //  8,388,608 B
  float* Mp   = (float*)(ws + 44040192);       //    131,072 B
  float* Sp   = (float*)(ws + 44171264);       //    131,072 B
  (void)in_sizes; (void)n_in; (void)out_size; (void)ws_size;

  k_prep <<<256, 256, 0, stream>>>(x, nw, xnT);
  k_wconv<<<2048, 256, 0, stream>>>(qkvw, ow, wqkv, owb);
  k_kv   <<<dim3(4,8,16), 256, 0, stream>>>(xnT, wqkv, ctxp, Mp, Sp);
  k_comb <<<128, 256, 0, stream>>>(ctxp, Mp, Sp, ctxT);
  k_qout <<<1024, 256, 0, stream>>>(xnT, wqkv, owb, ctxT, ob, onw, out);
}

// Round 3
// 260.028 us; speedup vs baseline: 18.2814x; 1.9044x over previous
//
#include <hip/hip_runtime.h>

#define C_ 256
#define N_ 4096
#define NH_ 8

typedef unsigned short u16;
typedef unsigned int u32;
typedef __attribute__((ext_vector_type(8))) short s8v;
typedef __attribute__((ext_vector_type(4))) float f4v;

#define MFMA16 __builtin_amdgcn_mfma_f32_16x16x32_bf16

__device__ __forceinline__ u16 f2bf(float f){ union{float f; u32 u;} v; v.f=f; return (u16)((v.u + 0x7FFFu + ((v.u>>16)&1u))>>16); }

__device__ __forceinline__ void gl_lds16(const u16* g, u16* l){
  __builtin_amdgcn_global_load_lds((const __attribute__((address_space(1))) u32*)g,
                                   (__attribute__((address_space(3))) u32*)l, 16, 0, 0);
}

// ---------------- kernel A1: pixel rnorm + write xnT[b][n][c] bf16 ----------------
__global__ __launch_bounds__(256) void k_prep(const float* __restrict__ x, const float* __restrict__ nw,
                                              u16* __restrict__ xnT){
  __shared__ float nws[256];
  const int tid = threadIdx.x;
  nws[tid] = nw[tid];
  __syncthreads();
  const int p = blockIdx.x*256 + tid;
  const int b = p>>12, n = p&4095;
  const float* xp = x + (size_t)b*(C_*N_) + n;
  float s = 0.f;
  #pragma unroll 8
  for (int c=0;c<C_;c++){ float v = xp[(size_t)c*N_]; s = fmaf(v,v,s); }
  const float r = 16.0f / fmaxf(sqrtf(s), 1e-12f);
  u16* o = xnT + (size_t)p*256;
  #pragma unroll 4
  for (int c=0;c<C_;c+=2){
    float v0 = xp[(size_t)c*N_]     * r * nws[c];
    float v1 = xp[(size_t)(c+1)*N_] * r * nws[c+1];
    *(u32*)(o + c) = (u32)f2bf(v0) | ((u32)f2bf(v1)<<16);
  }
}

// ---------------- kernel A2: weights -> bf16 ----------------
__global__ __launch_bounds__(256) void k_wconv(const float* __restrict__ qkvw, const float* __restrict__ ow,
                                               u16* __restrict__ wqkv, u16* __restrict__ owb){
  int i = blockIdx.x*256 + threadIdx.x;   // 524288 total
  if (i < 393216) wqkv[i] = f2bf(qkvw[i]);
  else            owb[i-393216] = f2bf(ow[i-393216]);
}

// ---------------- kernel B: K/V GEMM + flash softmax over n + ctx partials ----------------
__global__ __launch_bounds__(256,2) void k_kv(const u16* __restrict__ xnT, const u16* __restrict__ wqkv,
    float* __restrict__ ctxp, float* __restrict__ Mp, float* __restrict__ Sp){
  __shared__ float kbuf[64*133];
  __shared__ u16   vbuf[64*136];
  __shared__ float redm[64*4];
  __shared__ float reds[64*4];
  __shared__ float fbuf[64];
  const int ch=blockIdx.x, h=blockIdx.y, b=blockIdx.z;
  const int tid=threadIdx.x, w=tid>>6, l=tid&63, l15=l&15, lg=l>>4;
  const int sr = tid&63, sg = tid>>6;
  u16* pbuf = (u16*)kbuf;

  s8v ak[8], av[8];
  {
    const u16* wkp = wqkv + (size_t)(512 + h*64 + w*16 + l15)*256 + lg*8;
    const u16* wvp = wkp + 512*256;
    #pragma unroll
    for (int cs=0; cs<8; cs++){ ak[cs] = *(const s8v*)(wkp + cs*32); av[cs] = *(const s8v*)(wvp + cs*32); }
  }
  f4v acc[4];
  #pragma unroll
  for (int et=0;et<4;et++) acc[et] = (f4v){0.f,0.f,0.f,0.f};
  float M = -1e30f, S = 0.f;
  const u16* xb = xnT + (size_t)b*(4096*256);

  for (int t=0; t<8; ++t){
    const int n0 = ch*1024 + t*128;
    f4v kacc[8], vacc[8];
    #pragma unroll
    for (int ns=0;ns<8;ns++){ kacc[ns]=(f4v){0.f,0.f,0.f,0.f}; vacc[ns]=(f4v){0.f,0.f,0.f,0.f}; }
    #pragma unroll
    for (int ns=0; ns<8; ns++){
      const u16* rp = xb + (size_t)(n0 + ns*16 + l15)*256 + lg*8;
      #pragma unroll
      for (int cs=0; cs<8; cs++){
        s8v bfr = *(const s8v*)(rp + cs*32);
        kacc[ns] = MFMA16(ak[cs], bfr, kacc[ns], 0,0,0);
        vacc[ns] = MFMA16(av[cs], bfr, vacc[ns], 0,0,0);
      }
    }
    __syncthreads();
    #pragma unroll
    for (int ns=0; ns<8; ns++)
      #pragma unroll
      for (int j=0;j<4;j++){
        int row = w*16 + lg*4 + j, col = ns*16 + l15;
        kbuf[row*133+col] = kacc[ns][j];
        vbuf[row*136+col] = f2bf(vacc[ns][j]);
      }
    __syncthreads();
    float kv[32];
    #pragma unroll
    for (int i=0;i<32;i++) kv[i] = kbuf[sr*133 + sg*32 + i];
    float mx = kv[0];
    #pragma unroll
    for (int i=1;i<32;i++) mx = fmaxf(mx, kv[i]);
    redm[sr*4+sg] = mx;
    __syncthreads();
    float Mt = fmaxf(fmaxf(redm[sr*4],redm[sr*4+1]),fmaxf(redm[sr*4+2],redm[sr*4+3]));
    float Mn = fmaxf(M, Mt);
    float f  = __expf(M - Mn);
    float ps = 0.f;
    #pragma unroll
    for (int i=0;i<32;i++){
      float e = __expf(kv[i]-Mn);
      ps += e;
      pbuf[sr*136 + sg*32 + i] = f2bf(e);
    }
    reds[sr*4+sg] = ps;
    if (sg==0) fbuf[sr] = f;
    M = Mn;
    __syncthreads();
    S = S*f + (reds[sr*4]+reds[sr*4+1]+reds[sr*4+2]+reds[sr*4+3]);
    #pragma unroll
    for (int j=0;j<4;j++){
      float fj = fbuf[w*16 + lg*4 + j];
      #pragma unroll
      for (int et=0;et<4;et++) acc[et][j] *= fj;
    }
    #pragma unroll
    for (int ks=0; ks<4; ks++){
      s8v af = *(const s8v*)(pbuf + (w*16+l15)*136 + ks*32 + lg*8);
      #pragma unroll
      for (int et=0; et<4; et++){
        s8v bv = *(const s8v*)(vbuf + (et*16+l15)*136 + ks*32 + lg*8);
        acc[et] = MFMA16(af, bv, acc[et], 0,0,0);
      }
    }
  }
  float* cp = ctxp + (((size_t)ch*16 + b)*8 + h)*4096;
  #pragma unroll
  for (int et=0; et<4; et++)
    #pragma unroll
    for (int j=0;j<4;j++)
      cp[(w*16+lg*4+j)*64 + et*16+l15] = acc[et][j];
  if (sg==0){
    int rg = (b*8+h)*64 + sr;
    Mp[ch*8192+rg]=M; Sp[ch*8192+rg]=S;
  }
}

// ---------------- kernel C: combine chunk partials -> ctxT[b][h][e][d] bf16 ----------------
__global__ __launch_bounds__(256) void k_comb(const float* __restrict__ ctxp, const float* __restrict__ Mp,
    const float* __restrict__ Sp, u16* __restrict__ ctxT){
  __shared__ float fs[4][64];
  __shared__ float iS[64];
  const int bh = blockIdx.x, tid = threadIdx.x;
  if (tid < 64){
    int rg = bh*64 + tid;
    float m0=Mp[rg], m1=Mp[8192+rg], m2=Mp[16384+rg], m3=Mp[24576+rg];
    float Mg = fmaxf(fmaxf(m0,m1),fmaxf(m2,m3));
    float f0=__expf(m0-Mg), f1=__expf(m1-Mg), f2=__expf(m2-Mg), f3=__expf(m3-Mg);
    float Sg = Sp[rg]*f0 + Sp[8192+rg]*f1 + Sp[16384+rg]*f2 + Sp[24576+rg]*f3;
    fs[0][tid]=f0; fs[1][tid]=f1; fs[2][tid]=f2; fs[3][tid]=f3;
    iS[tid] = 1.0f / Sg;
  }
  __syncthreads();
  const int e = tid>>2, d0 = (tid&3)*16;
  const float* cpb = ctxp + (size_t)bh*4096;
  u16* op = ctxT + (size_t)bh*4096 + e*64 + d0;
  #pragma unroll
  for (int i=0;i<16;i++){
    int d = d0+i;
    float v = cpb[d*64+e]*fs[0][d] + cpb[524288+d*64+e]*fs[1][d]
            + cpb[1048576+d*64+e]*fs[2][d] + cpb[1572864+d*64+e]*fs[3][d];
    op[i] = f2bf(v * iS[d]);
  }
}

// ---------------- kernel D: q-GEMM + q-softmax + att + out-GEMM + bias + RMS ----------------
// grid 1024; per block 64 pixels (wave w owns 16). Per head: stage Wq_h + Wout_h in LDS
// (global_load_lds w16, XOR-swizzled via pre-swizzled source), ctx frags prefetched to regs.
__global__ __launch_bounds__(256,2) void k_qout(const u16* __restrict__ xnT, const u16* __restrict__ wqkv,
    const u16* __restrict__ owb, const u16* __restrict__ ctxT,
    const float* __restrict__ ob, const float* __restrict__ onw, float* __restrict__ out){
  __shared__ u16 WQ[64*256];     // 32KB, row-swizzled
  __shared__ u16 OWs[256*64];    // 32KB, row-swizzled
  __shared__ u16 qa[4][16*80];   // 10KB per-wave transpose buffer (qs and as share it)
  __shared__ float obs[256], onws[256];
  const int tid = threadIdx.x;
  obs[tid]=ob[tid]; onws[tid]=onw[tid];
  __syncthreads();
  const int w=tid>>6, l=tid&63, l15=l&15, lg=l>>4;
  const int swl = (l15&7)<<4;            // read-side XOR swizzle (bytes)
  const int blk=blockIdx.x, b=blk>>6, n0=(blk&63)*64 + w*16;
  const u16* xb = xnT + ((size_t)b*4096 + n0)*256;
  u16* qaw = qa[w];
  // resident xn A-frags (m = pixel row l15)
  s8v ax[8];
  #pragma unroll
  for (int cs=0;cs<8;cs++) ax[cs] = *(const s8v*)(xb + (size_t)l15*256 + cs*32 + lg*8);
  f4v oacc[16];
  #pragma unroll
  for (int mt=0;mt<16;mt++) oacc[mt] = (f4v){0.f,0.f,0.f,0.f};

  for (int h=0; h<8; ++h){
    __syncthreads();   // prev head's LDS readers done
    // stage Wq_h: rows w*16..+15, 8 issues x (2 rows = 1KB)
    {
      const u16* wqg = wqkv + (size_t)h*64*256;
      #pragma unroll
      for (int i=0;i<8;i++){
        int row = w*16 + i*2 + (l>>5);
        int colB = (l&31)*16;
        int scol = colB ^ ((row&7)<<4);
        gl_lds16(wqg + row*256 + (scol>>1), &WQ[(w*16 + i*2)*256]);
      }
    }
    // stage Wout_h cols h*64..+63: rows w*64..+63, 8 issues x (8 rows = 1KB)
    {
      #pragma unroll
      for (int i=0;i<8;i++){
        int row = w*64 + i*8 + (l>>3);
        int colB = (l&7)*16;
        int scol = colB ^ ((row&7)<<4);
        gl_lds16(owb + (size_t)row*512 + h*64 + (scol>>1), &OWs[(w*64 + i*8)*64]);
      }
    }
    // prefetch ctx B-frags into regs (latency hides under staging drain)
    s8v bc[8];
    {
      const u16* cxb = ctxT + ((size_t)(b*8+h))*4096;
      #pragma unroll
      for (int ks=0; ks<2; ks++)
        #pragma unroll
        for (int et=0; et<4; et++)
          bc[ks*4+et] = *(const s8v*)(cxb + (et*16+l15)*64 + ks*32 + lg*8);
    }
    __syncthreads();   // drains vmcnt(0): staging + bc complete
    // q-GEMM: D[n-local][dout]
    f4v qacc[4];
    #pragma unroll
    for (int dt=0;dt<4;dt++) qacc[dt] = (f4v){0.f,0.f,0.f,0.f};
    #pragma unroll
    for (int dt=0; dt<4; dt++){
      #pragma unroll
      for (int cs=0; cs<8; cs++){
        s8v bw = *(const s8v*)&WQ[(dt*16+l15)*256 + ((((cs<<6)+(lg<<4)) ^ swl)>>1)];
        qacc[dt] = MFMA16(ax[cs], bw, qacc[dt], 0,0,0);
      }
    }
    // softmax over d per pixel row (rows n = lg*4+j, cols d = dt*16+l15)
    #pragma unroll
    for (int j=0;j<4;j++){
      float m = fmaxf(fmaxf(qacc[0][j],qacc[1][j]),fmaxf(qacc[2][j],qacc[3][j]));
      #pragma unroll
      for (int d=1; d<16; d<<=1) m = fmaxf(m, __shfl_xor(m, d));
      float s = 0.f;
      #pragma unroll
      for (int dt=0;dt<4;dt++){ float e=__expf(qacc[dt][j]-m); qacc[dt][j]=e; s+=e; }
      #pragma unroll
      for (int d=1; d<16; d<<=1) s += __shfl_xor(s, d);
      float inv = 0.125f/s;
      #pragma unroll
      for (int dt=0;dt<4;dt++) qaw[(lg*4+j)*80 + dt*16+l15] = f2bf(qacc[dt][j]*inv);
    }
    // att-GEMM: D[n-local][e], B from prefetched ctx regs
    f4v aacc[4];
    #pragma unroll
    for (int et=0;et<4;et++) aacc[et] = (f4v){0.f,0.f,0.f,0.f};
    #pragma unroll
    for (int ks=0; ks<2; ks++){
      s8v aq = *(const s8v*)&qaw[l15*80 + ks*32 + lg*8];
      #pragma unroll
      for (int et=0; et<4; et++)
        aacc[et] = MFMA16(aq, bc[ks*4+et], aacc[et], 0,0,0);
    }
    #pragma unroll
    for (int et=0;et<4;et++)
      #pragma unroll
      for (int j=0;j<4;j++)
        qaw[(lg*4+j)*80 + et*16+l15] = f2bf(aacc[et][j]);
    // out-GEMM partial: D[cout][n-local], A from LDS OWs
    #pragma unroll
    for (int ks=0; ks<2; ks++){
      s8v ba = *(const s8v*)&qaw[l15*80 + ks*32 + lg*8];
      #pragma unroll
      for (int mt=0; mt<16; mt++){
        s8v aw = *(const s8v*)&OWs[(mt*16+l15)*64 + ((((ks<<6)+(lg<<4)) ^ swl)>>1)];
        oacc[mt] = MFMA16(aw, ba, oacc[mt], 0,0,0);
      }
    }
  }
  // bias + RMS over channels (per pixel col l15) + store
  float ss = 0.f;
  #pragma unroll
  for (int mt=0;mt<16;mt++)
    #pragma unroll
    for (int j=0;j<4;j++){
      float v = oacc[mt][j] + obs[mt*16+lg*4+j];
      oacc[mt][j] = v;
      ss = fmaf(v,v,ss);
    }
  ss += __shfl_xor(ss, 16);
  ss += __shfl_xor(ss, 32);
  const float r = 16.0f / fmaxf(sqrtf(ss), 1e-12f);
  float* op = out + (size_t)b*(256*4096) + n0 + l15;
  #pragma unroll
  for (int mt=0;mt<16;mt++)
    #pragma unroll
    for (int j=0;j<4;j++){
      int cout = mt*16+lg*4+j;
      op[(size_t)cout*4096] = oacc[mt][j] * r * onws[cout];
    }
}

extern "C" void kernel_launch(void* const* d_in, const int* in_sizes, int n_in,
                              void* d_out, int out_size, void* d_ws, size_t ws_size,
                              hipStream_t stream){
  const float* x    = (const float*)d_in[0];
  const float* nw   = (const float*)d_in[1];
  const float* qkvw = (const float*)d_in[2];
  const float* ow   = (const float*)d_in[3];
  const float* ob   = (const float*)d_in[4];
  const float* onw  = (const float*)d_in[5];
  float* out = (float*)d_out;
  char* ws = (char*)d_ws;
  u16*   xnT  = (u16*)(ws);                    // 33,554,432 B
  u16*   wqkv = (u16*)(ws + 33554432);         //    786,432 B
  u16*   owb  = (u16*)(ws + 34340864);         //    262,144 B
  u16*   ctxT = (u16*)(ws + 34603008);         //  1,048,576 B
  float* ctxp = (float*)(ws + 35651584);       //  8,388,608 B
  float* Mp   = (float*)(ws + 44040192);       //    131,072 B
  float* Sp   = (float*)(ws + 44171264);       //    131,072 B
  (void)in_sizes; (void)n_in; (void)out_size; (void)ws_size;

  k_prep <<<256, 256, 0, stream>>>(x, nw, xnT);
  k_wconv<<<2048, 256, 0, stream>>>(qkvw, ow, wqkv, owb);
  k_kv   <<<dim3(4,8,16), 256, 0, stream>>>(xnT, wqkv, ctxp, Mp, Sp);
  k_comb <<<128, 256, 0, stream>>>(ctxp, Mp, Sp, ctxT);
  k_qout <<<1024, 256, 0, stream>>>(xnT, wqkv, owb, ctxT, ob, onw, out);
}